// Round 4
// baseline (237.720 us; speedup 1.0000x reference)
//
#include <hip/hip_runtime.h>

typedef __bf16 bf16;
typedef __bf16 bf16x8 __attribute__((ext_vector_type(8)));
typedef float f32x4 __attribute__((ext_vector_type(4)));

__device__ __forceinline__ f32x4 mfma16(bf16x8 a, bf16x8 b, f32x4 c) {
  return __builtin_amdgcn_mfma_f32_16x16x32_bf16(a, b, c, 0, 0, 0);
}
__device__ __forceinline__ void gload16(const bf16* g, bf16* l) {
  __builtin_amdgcn_global_load_lds((const __attribute__((address_space(1))) unsigned int*)g,
                                   (__attribute__((address_space(3))) unsigned int*)l, 16, 0, 0);
}

// ---------------- convert x f32 -> bf16 (linear) ----------------
__global__ __launch_bounds__(256) void cvt_x_kernel(const float* __restrict__ in,
                                                    bf16* __restrict__ out, int n8) {
  int i = blockIdx.x * 256 + threadIdx.x;
  if (i >= n8) return;
  const float4* p = (const float4*)in + (size_t)i * 2;
  float4 f0 = p[0], f1 = p[1];
  bf16x8 o;
  o[0] = (bf16)f0.x; o[1] = (bf16)f0.y; o[2] = (bf16)f0.z; o[3] = (bf16)f0.w;
  o[4] = (bf16)f1.x; o[5] = (bf16)f1.y; o[6] = (bf16)f1.z; o[7] = (bf16)f1.w;
  *((bf16x8*)out + i) = o;
}

// ------- transpose-convert weight f32 [1024][1024] -> bf16 out[n][k]=in[k][n] -------
__global__ __launch_bounds__(256) void cvt_wt_kernel(const float* __restrict__ in,
                                                     bf16* __restrict__ out) {
  __shared__ float t[64][68];
  int bx = blockIdx.x & 15;
  int by = blockIdx.x >> 4;
  int tid = threadIdx.x;
  int r = tid >> 2, p = tid & 3;
  const float* src = in + (size_t)(by * 64 + r) * 1024 + bx * 64 + p * 16;
#pragma unroll
  for (int j = 0; j < 16; j += 4)
    *(float4*)&t[r][p * 16 + j] = *(const float4*)(src + j);
  __syncthreads();
  int n = tid >> 2, sp = tid & 3;
  bf16 tmp[16];
#pragma unroll
  for (int j = 0; j < 16; ++j) tmp[j] = (bf16)t[sp * 16 + j][n];
  bf16* dst = out + (size_t)(bx * 64 + n) * 1024 + by * 64 + sp * 16;
  *(bf16x8*)dst = *(bf16x8*)&tmp[0];
  *(bf16x8*)(dst + 8) = *(bf16x8*)&tmp[8];
}

// ---------------- fuse biases [bq|bk|bv] -> f32[3072] ----------------
__global__ void cvt_bias_kernel(const float* __restrict__ bq, const float* __restrict__ bk,
                                const float* __restrict__ bv, float* __restrict__ out) {
  int i = blockIdx.x * 256 + threadIdx.x;
  if (i < 1024) out[i] = bq[i];
  else if (i < 2048) out[i] = bk[i - 1024];
  else if (i < 3072) out[i] = bv[i - 2048];
}

// ---------------- bf16 GEMM: C[M][N] = A[M][K] * Bt[N][K]^T + bias, optional col-scale ----------------
template <int OUT_BF16>
__global__ __launch_bounds__(256) void gemm_bt_kernel(
    const bf16* __restrict__ A, const bf16* __restrict__ Bt,
    const float* __restrict__ bias, void* __restrict__ C,
    int M, int N, int K, int scale_cols, float scale_val) {
  __shared__ bf16 As[128][40];
  __shared__ bf16 Bs[128][40];
  int bn = blockIdx.x * 128, bm = blockIdx.y * 128;
  int tid = threadIdx.x;
  int l = tid & 63;
  int w = tid >> 6;
  int wr = w >> 1, wc = w & 1;
  int g = l >> 4, c = l & 15;
  int sr = tid >> 2, sk = (tid & 3) * 8;
  const bf16* Ap = A + (size_t)(bm + sr) * K + sk;
  const bf16* Bp = Bt + (size_t)(bn + sr) * K + sk;
  f32x4 acc[4][4] = {};
  for (int k0 = 0; k0 < K; k0 += 32) {
    bf16x8 a0 = *(const bf16x8*)(Ap + k0);
    bf16x8 a1 = *(const bf16x8*)(Ap + (size_t)64 * K + k0);
    bf16x8 b0 = *(const bf16x8*)(Bp + k0);
    bf16x8 b1 = *(const bf16x8*)(Bp + (size_t)64 * K + k0);
    __syncthreads();
    *(bf16x8*)&As[sr][sk] = a0;
    *(bf16x8*)&As[sr + 64][sk] = a1;
    *(bf16x8*)&Bs[sr][sk] = b0;
    *(bf16x8*)&Bs[sr + 64][sk] = b1;
    __syncthreads();
    bf16x8 af[4], bfr[4];
#pragma unroll
    for (int m = 0; m < 4; ++m) af[m] = *(const bf16x8*)&As[wr * 64 + m * 16 + c][g * 8];
#pragma unroll
    for (int n = 0; n < 4; ++n) bfr[n] = *(const bf16x8*)&Bs[wc * 64 + n * 16 + c][g * 8];
#pragma unroll
    for (int m = 0; m < 4; ++m)
#pragma unroll
      for (int n = 0; n < 4; ++n)
        acc[m][n] = mfma16(af[m], bfr[n], acc[m][n]);
  }
  int rowb = bm + wr * 64;
  int colb = bn + wc * 64;
#pragma unroll
  for (int n = 0; n < 4; ++n) {
    int col = colb + n * 16 + c;
    float bv = bias[col];
    float s = (col < scale_cols) ? scale_val : 1.0f;
#pragma unroll
    for (int m = 0; m < 4; ++m) {
      int row = rowb + m * 16 + g * 4;
#pragma unroll
      for (int j = 0; j < 4; ++j) {
        float v = (acc[m][n][j] + bv) * s;
        if (OUT_BF16)
          ((bf16*)C)[(size_t)(row + j) * N + col] = (bf16)v;
        else
          ((float*)C)[(size_t)(row + j) * N + col] = v;
      }
    }
  }
}

// ---------------- V transpose: qkv V-part -> vt[b*16+h][d=64][s=2048] ----------------
__global__ __launch_bounds__(256) void transpose_v_kernel(const bf16* __restrict__ qkv,
                                                          bf16* __restrict__ vt) {
  __shared__ bf16 t[64][72];
  int blk = blockIdx.x;
  int st = blk & 31;
  int h = (blk >> 5) & 15;
  int b = blk >> 9;
  int tid = threadIdx.x;
  int r = tid >> 2, p = tid & 3;
  const bf16* src = qkv + (size_t)(b * 2048 + st * 64 + r) * 3072 + 2048 + h * 64 + p * 16;
  *(bf16x8*)&t[r][p * 16] = *(const bf16x8*)src;
  *(bf16x8*)&t[r][p * 16 + 8] = *(const bf16x8*)(src + 8);
  __syncthreads();
  int d = tid >> 2, sp = tid & 3;
  bf16 tmp[16];
#pragma unroll
  for (int j = 0; j < 16; ++j) tmp[j] = t[sp * 16 + j][d];
  bf16* dst = vt + (size_t)((b * 16 + h) * 64 + d) * 2048 + st * 64 + sp * 16;
  *(bf16x8*)dst = *(bf16x8*)&tmp[0];
  *(bf16x8*)(dst + 8) = *(bf16x8*)&tmp[8];
}

// ---------------- flash attention with lag bias (no-max softmax, dbuf staging) ----------------
// grid 1024 = qt32 x h16 x b2 (XCD-swizzled); 4 waves x 16 q-rows, KVBLK=64.
// Identical validated 16x16 MFMA compute as round 2. Changes vs round 2:
//  - K/V double-buffered: stage tile t+1 (global_load_lds) before computing tile t,
//    ONE barrier per tile (the __syncthreads vmcnt/lgkm drain makes tile t+1 ready).
//  - bias/lag gathered from GLOBAL (L1-hot 2KB/8KB) on the idle VMEM pipe; no LDS
//    gather bank conflicts; bias*log2e applied via fmaf at use.
__global__ __launch_bounds__(256) void attn_kernel(
    const bf16* __restrict__ qkv, const bf16* __restrict__ vt,
    const int* __restrict__ lag, const float* __restrict__ lag_bias,
    bf16* __restrict__ out) {
  __shared__ __align__(16) bf16 Ks[2][64 * 64];
  __shared__ __align__(16) bf16 Vs[2][64 * 64];
  __shared__ __align__(16) bf16 Ps[4][16][72];

  int blk = blockIdx.x;
  blk = (blk & 7) * 128 + (blk >> 3);  // bijective XCD swizzle (1024 % 8 == 0)
  int qt = blk & 31;
  int h = (blk >> 5) & 15;
  int b = blk >> 9;
  int tid = threadIdx.x;
  int w = tid >> 6, l = tid & 63, g = l >> 4, c = l & 15;

  int q0 = qt * 64 + w * 16;
  const bf16* qbase = qkv + (size_t)(b * 2048 + q0) * 3072 + h * 64;
  bf16x8 qf[2];
  qf[0] = *(const bf16x8*)(qbase + (size_t)c * 3072 + g * 8);
  qf[1] = *(const bf16x8*)(qbase + (size_t)c * 3072 + 32 + g * 8);

  int lagq[4];
#pragma unroll
  for (int j = 0; j < 4; ++j) lagq[j] = lag[q0 + g * 4 + j];
  const float* __restrict__ lbh = lag_bias + h * 513;

  // fragment-read column offsets (swizzled)
  int swz = (c & 7) << 3;
  int off0 = (g * 8) ^ swz;
  int off1 = off0 ^ 32;

  // staging: thread covers 16B; wave w owns rows w*16..w*16+15 (two 8-row chunks)
  int r0 = w * 16 + (l >> 3);
  int colE = ((l & 7) ^ (l >> 3)) << 3;  // inverse-swizzled global column
  const bf16* kbase = qkv + (size_t)(b * 2048) * 3072 + 1024 + h * 64;
  const bf16* vbase = vt + (size_t)(b * 16 + h) * 64 * 2048;
  const bf16* kg0 = kbase + (size_t)r0 * 3072 + colE;
  const bf16* kg1 = kbase + (size_t)(r0 + 8) * 3072 + colE;
  const bf16* vg0 = vbase + (size_t)r0 * 2048 + colE;
  const bf16* vg1 = vbase + (size_t)(r0 + 8) * 2048 + colE;

  // prologue: stage tile 0 into buffer 0
  gload16(kg0, &Ks[0][w * 1024]);
  gload16(kg1, &Ks[0][w * 1024 + 512]);
  gload16(vg0, &Vs[0][w * 1024]);
  gload16(vg1, &Vs[0][w * 1024 + 512]);
  kg0 += 64 * 3072; kg1 += 64 * 3072; vg0 += 64; vg1 += 64;
  __syncthreads();

  f32x4 oacc[4] = {};
  float psum[4] = {0.f, 0.f, 0.f, 0.f};
  int cur = 0;

  for (int kt = 0; kt < 2048; kt += 64) {
    // issue next tile's staging first (prefetch in flight during compute)
    if (kt + 64 < 2048) {
      int nxt = cur ^ 1;
      gload16(kg0, &Ks[nxt][w * 1024]);
      gload16(kg1, &Ks[nxt][w * 1024 + 512]);
      gload16(vg0, &Vs[nxt][w * 1024]);
      gload16(vg1, &Vs[nxt][w * 1024 + 512]);
      kg0 += 64 * 3072; kg1 += 64 * 3072; vg0 += 64; vg1 += 64;
    }

    const bf16* Kb = Ks[cur];
    const bf16* Vb = Vs[cur];

    // QK^T: S[q = g*4+j][key = kb*16+c]
    f32x4 sf[4] = {};
    int lagk[4];
#pragma unroll
    for (int kb = 0; kb < 4; ++kb) {
      int row = kb * 16 + c;
      bf16x8 k0 = *(const bf16x8*)&Kb[row * 64 + off0];
      bf16x8 k1 = *(const bf16x8*)&Kb[row * 64 + off1];
      sf[kb] = mfma16(qf[0], k0, sf[kb]);
      sf[kb] = mfma16(qf[1], k1, sf[kb]);
      lagk[kb] = lag[kt + kb * 16 + c];
    }
    // no-max softmax: p = exp2(s + bias*log2e), bias gathered from global (L1)
#pragma unroll
    for (int kb = 0; kb < 4; ++kb) {
#pragma unroll
      for (int j = 0; j < 4; ++j) {
        int ld = lagq[j] - lagk[kb];
        ld = ld < 0 ? -ld : ld;
        float p = __builtin_amdgcn_exp2f(fmaf(lbh[ld], 1.44269504f, sf[kb][j]));
        psum[j] += p;
        Ps[w][g * 4 + j][kb * 16 + c] = (bf16)p;
      }
    }
    asm volatile("s_waitcnt lgkmcnt(0)" ::: "memory");
    bf16x8 pa0 = *(const bf16x8*)&Ps[w][c][g * 8];
    bf16x8 pa1 = *(const bf16x8*)&Ps[w][c][32 + g * 8];
#pragma unroll
    for (int n = 0; n < 4; ++n) {
      int row = n * 16 + c;
      bf16x8 v0 = *(const bf16x8*)&Vb[row * 64 + off0];
      bf16x8 v1 = *(const bf16x8*)&Vb[row * 64 + off1];
      oacc[n] = mfma16(pa0, v0, oacc[n]);
      oacc[n] = mfma16(pa1, v1, oacc[n]);
    }

    __syncthreads();  // drains vmcnt (stage t+1 done) + closes reads of buf[cur]
    cur ^= 1;
  }

  // one-time row-sum reduction across the 16 c-lanes, then normalize+store
#pragma unroll
  for (int j = 0; j < 4; ++j) {
    float s = psum[j];
    s += __shfl_xor(s, 1);
    s += __shfl_xor(s, 2);
    s += __shfl_xor(s, 4);
    s += __shfl_xor(s, 8);
    float inv = 1.f / s;
    bf16* ob = out + (size_t)(b * 2048 + q0 + g * 4 + j) * 1024 + h * 64;
#pragma unroll
    for (int n = 0; n < 4; ++n)
      ob[n * 16 + c] = (bf16)(oacc[n][j] * inv);
  }
}

extern "C" void kernel_launch(void* const* d_in, const int* in_sizes, int n_in,
                              void* d_out, int out_size, void* d_ws, size_t ws_size,
                              hipStream_t stream) {
  const float* x        = (const float*)d_in[0];
  const int*   lag      = (const int*)d_in[1];
  const float* wq       = (const float*)d_in[2];
  const float* bq       = (const float*)d_in[3];
  const float* wk       = (const float*)d_in[4];
  const float* bk       = (const float*)d_in[5];
  const float* wv       = (const float*)d_in[6];
  const float* bv       = (const float*)d_in[7];
  const float* wo       = (const float*)d_in[8];
  const float* bo       = (const float*)d_in[9];
  const float* lag_bias = (const float*)d_in[10];

  char* ws = (char*)d_ws;
  bf16*  xb    = (bf16*)ws;                        // 8 MB
  bf16*  wqkvt = (bf16*)(ws + (8u  << 20));        // 6 MB
  bf16*  wot   = (bf16*)(ws + (14u << 20));        // 2 MB
  float* bqkv  = (float*)(ws + (16u << 20));       // 12 KB
  bf16*  qkv   = (bf16*)(ws + (17u << 20));        // 24 MB
  bf16*  vtb   = (bf16*)(ws + (41u << 20));        // 8 MB
  bf16*  aout  = (bf16*)(ws + (49u << 20));        // 8 MB

  cvt_x_kernel<<<2048, 256, 0, stream>>>(x, xb, 524288);
  cvt_wt_kernel<<<256, 256, 0, stream>>>(wq, wqkvt);
  cvt_wt_kernel<<<256, 256, 0, stream>>>(wk, wqkvt + (1u << 20));
  cvt_wt_kernel<<<256, 256, 0, stream>>>(wv, wqkvt + (2u << 20));
  cvt_wt_kernel<<<256, 256, 0, stream>>>(wo, wot);
  cvt_bias_kernel<<<12, 256, 0, stream>>>(bq, bk, bv, bqkv);
  gemm_bt_kernel<1><<<dim3(24, 32), 256, 0, stream>>>(
      xb, wqkvt, bqkv, qkv, 4096, 3072, 1024, 1024, 0.125f * 1.44269504f);
  transpose_v_kernel<<<1024, 256, 0, stream>>>(qkv, vtb);
  attn_kernel<<<1024, 256, 0, stream>>>(qkv, vtb, lag, lag_bias, aout);
  gemm_bt_kernel<0><<<dim3(8, 32), 256, 0, stream>>>(
      aout, wot, bo, (float*)d_out, 4096, 1024, 1024, 0, 1.0f);
}

// Round 5
// 171.027 us; speedup vs baseline: 1.3900x; 1.3900x over previous
//
#include <hip/hip_runtime.h>

typedef __bf16 bf16;
typedef __bf16 bf16x8 __attribute__((ext_vector_type(8)));
typedef float f32x4 __attribute__((ext_vector_type(4)));

__device__ __forceinline__ f32x4 mfma16(bf16x8 a, bf16x8 b, f32x4 c) {
  return __builtin_amdgcn_mfma_f32_16x16x32_bf16(a, b, c, 0, 0, 0);
}
__device__ __forceinline__ void gload16(const bf16* g, bf16* l) {
  __builtin_amdgcn_global_load_lds((const __attribute__((address_space(1))) unsigned int*)g,
                                   (__attribute__((address_space(3))) unsigned int*)l, 16, 0, 0);
}

// ---------------- convert x f32 -> bf16 (linear) ----------------
__global__ __launch_bounds__(256) void cvt_x_kernel(const float* __restrict__ in,
                                                    bf16* __restrict__ out, int n8) {
  int i = blockIdx.x * 256 + threadIdx.x;
  if (i >= n8) return;
  const float4* p = (const float4*)in + (size_t)i * 2;
  float4 f0 = p[0], f1 = p[1];
  bf16x8 o;
  o[0] = (bf16)f0.x; o[1] = (bf16)f0.y; o[2] = (bf16)f0.z; o[3] = (bf16)f0.w;
  o[4] = (bf16)f1.x; o[5] = (bf16)f1.y; o[6] = (bf16)f1.z; o[7] = (bf16)f1.w;
  *((bf16x8*)out + i) = o;
}

// ------- transpose-convert weight f32 [1024][1024] -> bf16 out[n][k]=in[k][n] -------
__global__ __launch_bounds__(256) void cvt_wt_kernel(const float* __restrict__ in,
                                                     bf16* __restrict__ out) {
  __shared__ float t[64][68];
  int bx = blockIdx.x & 15;
  int by = blockIdx.x >> 4;
  int tid = threadIdx.x;
  int r = tid >> 2, p = tid & 3;
  const float* src = in + (size_t)(by * 64 + r) * 1024 + bx * 64 + p * 16;
#pragma unroll
  for (int j = 0; j < 16; j += 4)
    *(float4*)&t[r][p * 16 + j] = *(const float4*)(src + j);
  __syncthreads();
  int n = tid >> 2, sp = tid & 3;
  bf16 tmp[16];
#pragma unroll
  for (int j = 0; j < 16; ++j) tmp[j] = (bf16)t[sp * 16 + j][n];
  bf16* dst = out + (size_t)(bx * 64 + n) * 1024 + by * 64 + sp * 16;
  *(bf16x8*)dst = *(bf16x8*)&tmp[0];
  *(bf16x8*)(dst + 8) = *(bf16x8*)&tmp[8];
}

// ---------------- fuse biases [bq|bk|bv] -> f32[3072] ----------------
__global__ void cvt_bias_kernel(const float* __restrict__ bq, const float* __restrict__ bk,
                                const float* __restrict__ bv, float* __restrict__ out) {
  int i = blockIdx.x * 256 + threadIdx.x;
  if (i < 1024) out[i] = bq[i];
  else if (i < 2048) out[i] = bk[i - 1024];
  else if (i < 3072) out[i] = bv[i - 2048];
}

// ---------------- bf16 GEMM: C[M][N] = A[M][K] * Bt[N][K]^T + bias, optional col-scale ----------------
template <int OUT_BF16>
__global__ __launch_bounds__(256) void gemm_bt_kernel(
    const bf16* __restrict__ A, const bf16* __restrict__ Bt,
    const float* __restrict__ bias, void* __restrict__ C,
    int M, int N, int K, int scale_cols, float scale_val) {
  __shared__ bf16 As[128][40];
  __shared__ bf16 Bs[128][40];
  int bn = blockIdx.x * 128, bm = blockIdx.y * 128;
  int tid = threadIdx.x;
  int l = tid & 63;
  int w = tid >> 6;
  int wr = w >> 1, wc = w & 1;
  int g = l >> 4, c = l & 15;
  int sr = tid >> 2, sk = (tid & 3) * 8;
  const bf16* Ap = A + (size_t)(bm + sr) * K + sk;
  const bf16* Bp = Bt + (size_t)(bn + sr) * K + sk;
  f32x4 acc[4][4] = {};
  for (int k0 = 0; k0 < K; k0 += 32) {
    bf16x8 a0 = *(const bf16x8*)(Ap + k0);
    bf16x8 a1 = *(const bf16x8*)(Ap + (size_t)64 * K + k0);
    bf16x8 b0 = *(const bf16x8*)(Bp + k0);
    bf16x8 b1 = *(const bf16x8*)(Bp + (size_t)64 * K + k0);
    __syncthreads();
    *(bf16x8*)&As[sr][sk] = a0;
    *(bf16x8*)&As[sr + 64][sk] = a1;
    *(bf16x8*)&Bs[sr][sk] = b0;
    *(bf16x8*)&Bs[sr + 64][sk] = b1;
    __syncthreads();
    bf16x8 af[4], bfr[4];
#pragma unroll
    for (int m = 0; m < 4; ++m) af[m] = *(const bf16x8*)&As[wr * 64 + m * 16 + c][g * 8];
#pragma unroll
    for (int n = 0; n < 4; ++n) bfr[n] = *(const bf16x8*)&Bs[wc * 64 + n * 16 + c][g * 8];
#pragma unroll
    for (int m = 0; m < 4; ++m)
#pragma unroll
      for (int n = 0; n < 4; ++n)
        acc[m][n] = mfma16(af[m], bfr[n], acc[m][n]);
  }
  int rowb = bm + wr * 64;
  int colb = bn + wc * 64;
#pragma unroll
  for (int n = 0; n < 4; ++n) {
    int col = colb + n * 16 + c;
    float bv = bias[col];
    float s = (col < scale_cols) ? scale_val : 1.0f;
#pragma unroll
    for (int m = 0; m < 4; ++m) {
      int row = rowb + m * 16 + g * 4;
#pragma unroll
      for (int j = 0; j < 4; ++j) {
        float v = (acc[m][n][j] + bv) * s;
        if (OUT_BF16)
          ((bf16*)C)[(size_t)(row + j) * N + col] = (bf16)v;
        else
          ((float*)C)[(size_t)(row + j) * N + col] = v;
      }
    }
  }
}

// ---------------- V transpose: qkv V-part -> vt[b*16+h][d=64][s=2048] ----------------
__global__ __launch_bounds__(256) void transpose_v_kernel(const bf16* __restrict__ qkv,
                                                          bf16* __restrict__ vt) {
  __shared__ bf16 t[64][72];
  int blk = blockIdx.x;
  int st = blk & 31;
  int h = (blk >> 5) & 15;
  int b = blk >> 9;
  int tid = threadIdx.x;
  int r = tid >> 2, p = tid & 3;
  const bf16* src = qkv + (size_t)(b * 2048 + st * 64 + r) * 3072 + 2048 + h * 64 + p * 16;
  *(bf16x8*)&t[r][p * 16] = *(const bf16x8*)src;
  *(bf16x8*)&t[r][p * 16 + 8] = *(const bf16x8*)(src + 8);
  __syncthreads();
  int d = tid >> 2, sp = tid & 3;
  bf16 tmp[16];
#pragma unroll
  for (int j = 0; j < 16; ++j) tmp[j] = t[sp * 16 + j][d];
  bf16* dst = vt + (size_t)((b * 16 + h) * 64 + d) * 2048 + st * 64 + sp * 16;
  *(bf16x8*)dst = *(bf16x8*)&tmp[0];
  *(bf16x8*)(dst + 8) = *(bf16x8*)&tmp[8];
}

// ---------------- flash attention with lag bias ----------------
// grid 512 = qt16 x h16 x b2 (XCD-swizzled: each (b,h) pinned to one XCD => K/V L2-hot).
// 4 waves x 32 q-rows = 128 q/block; KVBLK=64.
// Round-2-validated compute (16x16 MFMA, no-max exp2 softmax, LDS bias/lag gathers,
// Ps LDS bounce) extended to 2 q-blocks per wave (round-1-validated m-loop).
// Double-buffer via DISTINCT static LDS objects (Ks0/Ks1, Vs0/Vs1) + 2x-unrolled loop:
// compiler proves staging(next) and ds_read(cur) disjoint => no false vmcnt wait; the
// __syncthreads() vmcnt drain at phase end is the staging fence (T3-minimum recipe).
__global__ __launch_bounds__(256) void attn_kernel(
    const bf16* __restrict__ qkv, const bf16* __restrict__ vt,
    const int* __restrict__ lag, const float* __restrict__ lag_bias,
    bf16* __restrict__ out) {
  __shared__ __align__(16) bf16 Ks0[64 * 64];
  __shared__ __align__(16) bf16 Vs0[64 * 64];
  __shared__ __align__(16) bf16 Ks1[64 * 64];
  __shared__ __align__(16) bf16 Vs1[64 * 64];
  __shared__ __align__(16) bf16 Ps[4][32][72];
  __shared__ float bias_s[516];
  __shared__ int lag_s[2048];

  int blk = blockIdx.x;
  blk = (blk & 7) * 64 + (blk >> 3);  // bijective XCD swizzle (512 % 8 == 0)
  int qt = blk & 15;
  int h = (blk >> 4) & 15;
  int b = blk >> 8;
  int tid = threadIdx.x;
  int w = tid >> 6, l = tid & 63, g = l >> 4, c = l & 15;

  for (int i = tid; i < 513; i += 256) bias_s[i] = lag_bias[h * 513 + i] * 1.44269504f;
  for (int i = tid; i < 2048; i += 256) lag_s[i] = lag[i];

  int q0 = qt * 128 + w * 32;
  const bf16* qbase = qkv + (size_t)(b * 2048 + q0) * 3072 + h * 64;
  bf16x8 qf[2][2];
#pragma unroll
  for (int m = 0; m < 2; ++m)
#pragma unroll
    for (int kh = 0; kh < 2; ++kh)
      qf[m][kh] = *(const bf16x8*)(qbase + (size_t)(m * 16 + c) * 3072 + kh * 32 + g * 8);

  // fragment-read column offsets (XOR-swizzled LDS layout)
  int swz = (c & 7) << 3;
  int off0 = (g * 8) ^ swz;
  int off1 = off0 ^ 32;

  // staging: thread covers 16B; wave w owns rows w*16..w*16+15 (two 8-row chunks)
  int r0 = w * 16 + (l >> 3);
  int colE = ((l & 7) ^ (l >> 3)) << 3;  // inverse-swizzled global column
  const bf16* kbase = qkv + (size_t)(b * 2048) * 3072 + 1024 + h * 64;
  const bf16* vbase = vt + (size_t)(b * 16 + h) * 64 * 2048;
  const bf16* kg0 = kbase + (size_t)r0 * 3072 + colE;
  const bf16* kg1 = kbase + (size_t)(r0 + 8) * 3072 + colE;
  const bf16* vg0 = vbase + (size_t)r0 * 2048 + colE;
  const bf16* vg1 = vbase + (size_t)(r0 + 8) * 2048 + colE;

#define STAGE(KD, VD)                    \
  do {                                   \
    gload16(kg0, KD + w * 1024);         \
    gload16(kg1, KD + w * 1024 + 512);   \
    gload16(vg0, VD + w * 1024);         \
    gload16(vg1, VD + w * 1024 + 512);   \
    kg0 += 64 * 3072; kg1 += 64 * 3072;  \
    vg0 += 64; vg1 += 64;                \
  } while (0)

  // prologue: stage tile 0 into buffer 0; barrier drains vmcnt + bias/lag writes
  STAGE(Ks0, Vs0);
  __syncthreads();

  int lagq[2][4];
#pragma unroll
  for (int m = 0; m < 2; ++m)
#pragma unroll
    for (int j = 0; j < 4; ++j) lagq[m][j] = lag_s[q0 + m * 16 + g * 4 + j];

  f32x4 oacc[2][4] = {};
  float psum[2][4] = {};

#define TILE(KB, VB, KT)                                                          \
  do {                                                                            \
    f32x4 sf[2][4] = {};                                                          \
    int lagk[4];                                                                  \
    _Pragma("unroll") for (int kb = 0; kb < 4; ++kb) {                            \
      int row = kb * 16 + c;                                                      \
      bf16x8 k0 = *(const bf16x8*)&KB[row * 64 + off0];                           \
      bf16x8 k1 = *(const bf16x8*)&KB[row * 64 + off1];                           \
      sf[0][kb] = mfma16(qf[0][0], k0, sf[0][kb]);                                \
      sf[0][kb] = mfma16(qf[0][1], k1, sf[0][kb]);                                \
      sf[1][kb] = mfma16(qf[1][0], k0, sf[1][kb]);                                \
      sf[1][kb] = mfma16(qf[1][1], k1, sf[1][kb]);                                \
      lagk[kb] = lag_s[(KT) + kb * 16 + c];                                       \
    }                                                                             \
    _Pragma("unroll") for (int m = 0; m < 2; ++m)                                 \
    _Pragma("unroll") for (int kb = 0; kb < 4; ++kb)                              \
    _Pragma("unroll") for (int j = 0; j < 4; ++j) {                               \
      int ld = lagq[m][j] - lagk[kb];                                             \
      ld = ld < 0 ? -ld : ld;                                                     \
      float p = __builtin_amdgcn_exp2f(sf[m][kb][j] + bias_s[ld]);                \
      psum[m][j] += p;                                                            \
      Ps[w][m * 16 + g * 4 + j][kb * 16 + c] = (bf16)p;                           \
    }                                                                             \
    asm volatile("s_waitcnt lgkmcnt(0)" ::: "memory");                            \
    _Pragma("unroll") for (int ph = 0; ph < 2; ++ph) {                            \
      bf16x8 pa0 = *(const bf16x8*)&Ps[w][c][ph * 32 + g * 8];                    \
      bf16x8 pa1 = *(const bf16x8*)&Ps[w][16 + c][ph * 32 + g * 8];               \
      int voff = ph ? off1 : off0;                                                \
      _Pragma("unroll") for (int n = 0; n < 4; ++n) {                             \
        bf16x8 vf = *(const bf16x8*)&VB[(n * 16 + c) * 64 + voff];                \
        oacc[0][n] = mfma16(pa0, vf, oacc[0][n]);                                 \
        oacc[1][n] = mfma16(pa1, vf, oacc[1][n]);                                 \
      }                                                                           \
    }                                                                             \
  } while (0)

  for (int kt = 0; kt < 2048; kt += 128) {
    if (kt + 64 < 2048) STAGE(Ks1, Vs1);
    TILE(Ks0, Vs0, kt);
    __syncthreads();  // drains vmcnt: Ks1/Vs1 ready; closes Ks0/Vs0 reads
    if (kt + 128 < 2048) STAGE(Ks0, Vs0);
    TILE(Ks1, Vs1, kt + 64);
    __syncthreads();
  }

  // one-time row-sum reduction across the 16 c-lanes, then normalize+store
#pragma unroll
  for (int m = 0; m < 2; ++m) {
#pragma unroll
    for (int j = 0; j < 4; ++j) {
      float s = psum[m][j];
      s += __shfl_xor(s, 1);
      s += __shfl_xor(s, 2);
      s += __shfl_xor(s, 4);
      s += __shfl_xor(s, 8);
      float inv = 1.f / s;
      bf16* ob = out + (size_t)(b * 2048 + q0 + m * 16 + g * 4 + j) * 1024 + h * 64;
#pragma unroll
      for (int n = 0; n < 4; ++n)
        ob[n * 16 + c] = (bf16)(oacc[m][n][j] * inv);
    }
  }
#undef STAGE
#undef TILE
}

extern "C" void kernel_launch(void* const* d_in, const int* in_sizes, int n_in,
                              void* d_out, int out_size, void* d_ws, size_t ws_size,
                              hipStream_t stream) {
  const float* x        = (const float*)d_in[0];
  const int*   lag      = (const int*)d_in[1];
  const float* wq       = (const float*)d_in[2];
  const float* bq       = (const float*)d_in[3];
  const float* wk       = (const float*)d_in[4];
  const float* bk       = (const float*)d_in[5];
  const float* wv       = (const float*)d_in[6];
  const float* bv       = (const float*)d_in[7];
  const float* wo       = (const float*)d_in[8];
  const float* bo       = (const float*)d_in[9];
  const float* lag_bias = (const float*)d_in[10];

  char* ws = (char*)d_ws;
  bf16*  xb    = (bf16*)ws;                        // 8 MB
  bf16*  wqkvt = (bf16*)(ws + (8u  << 20));        // 6 MB
  bf16*  wot   = (bf16*)(ws + (14u << 20));        // 2 MB
  float* bqkv  = (float*)(ws + (16u << 20));       // 12 KB
  bf16*  qkv   = (bf16*)(ws + (17u << 20));        // 24 MB
  bf16*  vtb   = (bf16*)(ws + (41u << 20));        // 8 MB
  bf16*  aout  = (bf16*)(ws + (49u << 20));        // 8 MB

  cvt_x_kernel<<<2048, 256, 0, stream>>>(x, xb, 524288);
  cvt_wt_kernel<<<256, 256, 0, stream>>>(wq, wqkvt);
  cvt_wt_kernel<<<256, 256, 0, stream>>>(wk, wqkvt + (1u << 20));
  cvt_wt_kernel<<<256, 256, 0, stream>>>(wv, wqkvt + (2u << 20));
  cvt_wt_kernel<<<256, 256, 0, stream>>>(wo, wot);
  cvt_bias_kernel<<<12, 256, 0, stream>>>(bq, bk, bv, bqkv);
  gemm_bt_kernel<1><<<dim3(24, 32), 256, 0, stream>>>(
      xb, wqkvt, bqkv, qkv, 4096, 3072, 1024, 1024, 0.125f * 1.44269504f);
  transpose_v_kernel<<<1024, 256, 0, stream>>>(qkv, vtb);
  attn_kernel<<<512, 256, 0, stream>>>(qkv, vtb, lag, lag_bias, aout);
  gemm_bt_kernel<0><<<dim3(8, 32), 256, 0, stream>>>(
      aout, wot, bo, (float*)d_out, 4096, 1024, 1024, 0, 1.0f);
}

// Round 7
// 170.783 us; speedup vs baseline: 1.3919x; 1.0014x over previous
//
#include <hip/hip_runtime.h>

typedef __bf16 bf16;
typedef __bf16 bf16x8 __attribute__((ext_vector_type(8)));
typedef float f32x4 __attribute__((ext_vector_type(4)));

__device__ __forceinline__ f32x4 mfma16(bf16x8 a, bf16x8 b, f32x4 c) {
  return __builtin_amdgcn_mfma_f32_16x16x32_bf16(a, b, c, 0, 0, 0);
}
__device__ __forceinline__ void gload16(const bf16* g, bf16* l) {
  __builtin_amdgcn_global_load_lds((const __attribute__((address_space(1))) unsigned int*)g,
                                   (__attribute__((address_space(3))) unsigned int*)l, 16, 0, 0);
}

// ---------------- convert x f32 -> bf16 (linear) ----------------
__global__ __launch_bounds__(256) void cvt_x_kernel(const float* __restrict__ in,
                                                    bf16* __restrict__ out, int n8) {
  int i = blockIdx.x * 256 + threadIdx.x;
  if (i >= n8) return;
  const float4* p = (const float4*)in + (size_t)i * 2;
  float4 f0 = p[0], f1 = p[1];
  bf16x8 o;
  o[0] = (bf16)f0.x; o[1] = (bf16)f0.y; o[2] = (bf16)f0.z; o[3] = (bf16)f0.w;
  o[4] = (bf16)f1.x; o[5] = (bf16)f1.y; o[6] = (bf16)f1.z; o[7] = (bf16)f1.w;
  *((bf16x8*)out + i) = o;
}

// ------- transpose-convert weight f32 [1024][1024] -> bf16 out[n][k]=in[k][n] -------
__global__ __launch_bounds__(256) void cvt_wt_kernel(const float* __restrict__ in,
                                                     bf16* __restrict__ out) {
  __shared__ float t[64][68];
  int bx = blockIdx.x & 15;
  int by = blockIdx.x >> 4;
  int tid = threadIdx.x;
  int r = tid >> 2, p = tid & 3;
  const float* src = in + (size_t)(by * 64 + r) * 1024 + bx * 64 + p * 16;
#pragma unroll
  for (int j = 0; j < 16; j += 4)
    *(float4*)&t[r][p * 16 + j] = *(const float4*)(src + j);
  __syncthreads();
  int n = tid >> 2, sp = tid & 3;
  bf16 tmp[16];
#pragma unroll
  for (int j = 0; j < 16; ++j) tmp[j] = (bf16)t[sp * 16 + j][n];
  bf16* dst = out + (size_t)(bx * 64 + n) * 1024 + by * 64 + sp * 16;
  *(bf16x8*)dst = *(bf16x8*)&tmp[0];
  *(bf16x8*)(dst + 8) = *(bf16x8*)&tmp[8];
}

// ---------------- fuse biases [bq|bk|bv] -> f32[3072] ----------------
__global__ void cvt_bias_kernel(const float* __restrict__ bq, const float* __restrict__ bk,
                                const float* __restrict__ bv, float* __restrict__ out) {
  int i = blockIdx.x * 256 + threadIdx.x;
  if (i < 1024) out[i] = bq[i];
  else if (i < 2048) out[i] = bk[i - 1024];
  else if (i < 3072) out[i] = bv[i - 2048];
}

// ---------------- bf16 GEMM: C[M][N] = A[M][K] * Bt[N][K]^T + bias, optional col-scale ----------------
// 128x128 tile, BK=64, 256 threads (2x2 waves of 64x64). K/V-staging via global_load_lds
// width=16 into linear [128][64] LDS tiles with (row&7) XOR chunk swizzle — the exact
// geometry validated in the attn kernel (R2/R5). Frag reads are quarter-wave conflict-free.
template <int OUT_BF16>
__global__ __launch_bounds__(256) void gemm_bt_kernel(
    const bf16* __restrict__ A, const bf16* __restrict__ Bt,
    const float* __restrict__ bias, void* __restrict__ C,
    int M, int N, int K, int scale_cols, float scale_val) {
  __shared__ __align__(16) bf16 As[128 * 64];
  __shared__ __align__(16) bf16 Bs[128 * 64];
  int bn = blockIdx.x * 128, bm = blockIdx.y * 128;
  int tid = threadIdx.x;
  int l = tid & 63;
  int w = tid >> 6;
  int wr = w >> 1, wc = w & 1;
  int g = l >> 4, c = l & 15;
  int swz = (c & 7) << 3;

  // staging: per gload, lane l covers LDS row (base + (l>>3)), col chunk (l&7);
  // global source column pre-swizzled so LDS ends up [row][chunk ^ (row&7)]
  int srow = l >> 3;                       // 0..7 within an 8-row gload
  int scol = ((l & 7) ^ srow) << 3;        // inverse-swizzled global column (elems)
  const bf16* Ap = A + (size_t)(bm + w * 32 + srow) * K + scol;
  const bf16* Bp = Bt + (size_t)(bn + w * 32 + srow) * K + scol;
  bf16* AsW = As + w * 32 * 64;            // wave-uniform LDS bases
  bf16* BsW = Bs + w * 32 * 64;

  f32x4 acc[4][4] = {};
  for (int k0 = 0; k0 < K; k0 += 64) {
    __syncthreads();  // close previous tile's frag reads
#pragma unroll
    for (int i = 0; i < 4; ++i) {
      gload16(Ap + (size_t)(8 * i) * K + k0, AsW + i * 512);
      gload16(Bp + (size_t)(8 * i) * K + k0, BsW + i * 512);
    }
    __syncthreads();  // vmcnt drained => tile ready
#pragma unroll
    for (int kh = 0; kh < 2; ++kh) {
      bf16x8 af[4], bfr[4];
#pragma unroll
      for (int m = 0; m < 4; ++m)
        af[m] = *(const bf16x8*)&As[(wr * 64 + m * 16 + c) * 64 + ((kh * 32 + g * 8) ^ swz)];
#pragma unroll
      for (int n = 0; n < 4; ++n)
        bfr[n] = *(const bf16x8*)&Bs[(wc * 64 + n * 16 + c) * 64 + ((kh * 32 + g * 8) ^ swz)];
#pragma unroll
      for (int m = 0; m < 4; ++m)
#pragma unroll
        for (int n = 0; n < 4; ++n)
          acc[m][n] = mfma16(af[m], bfr[n], acc[m][n]);
    }
  }
  int rowb = bm + wr * 64;
  int colb = bn + wc * 64;
#pragma unroll
  for (int n = 0; n < 4; ++n) {
    int col = colb + n * 16 + c;
    float bv = bias[col];
    float s = (col < scale_cols) ? scale_val : 1.0f;
#pragma unroll
    for (int m = 0; m < 4; ++m) {
      int row = rowb + m * 16 + g * 4;
#pragma unroll
      for (int j = 0; j < 4; ++j) {
        float v = (acc[m][n][j] + bv) * s;
        if (OUT_BF16)
          ((bf16*)C)[(size_t)(row + j) * N + col] = (bf16)v;
        else
          ((float*)C)[(size_t)(row + j) * N + col] = v;
      }
    }
  }
}

// ---------------- V transpose: qkv V-part -> vt[b*16+h][d=64][s=2048] ----------------
__global__ __launch_bounds__(256) void transpose_v_kernel(const bf16* __restrict__ qkv,
                                                          bf16* __restrict__ vt) {
  __shared__ bf16 t[64][72];
  int blk = blockIdx.x;
  int st = blk & 31;
  int h = (blk >> 5) & 15;
  int b = blk >> 9;
  int tid = threadIdx.x;
  int r = tid >> 2, p = tid & 3;
  const bf16* src = qkv + (size_t)(b * 2048 + st * 64 + r) * 3072 + 2048 + h * 64 + p * 16;
  *(bf16x8*)&t[r][p * 16] = *(const bf16x8*)src;
  *(bf16x8*)&t[r][p * 16 + 8] = *(const bf16x8*)(src + 8);
  __syncthreads();
  int d = tid >> 2, sp = tid & 3;
  bf16 tmp[16];
#pragma unroll
  for (int j = 0; j < 16; ++j) tmp[j] = t[sp * 16 + j][d];
  bf16* dst = vt + (size_t)((b * 16 + h) * 64 + d) * 2048 + st * 64 + sp * 16;
  *(bf16x8*)dst = *(bf16x8*)&tmp[0];
  *(bf16x8*)(dst + 8) = *(bf16x8*)&tmp[8];
}

// ---------------- flash attention with lag bias (R5-validated + setprio) ----------------
__global__ __launch_bounds__(256) void attn_kernel(
    const bf16* __restrict__ qkv, const bf16* __restrict__ vt,
    const int* __restrict__ lag, const float* __restrict__ lag_bias,
    bf16* __restrict__ out) {
  __shared__ __align__(16) bf16 Ks0[64 * 64];
  __shared__ __align__(16) bf16 Vs0[64 * 64];
  __shared__ __align__(16) bf16 Ks1[64 * 64];
  __shared__ __align__(16) bf16 Vs1[64 * 64];
  __shared__ __align__(16) bf16 Ps[4][32][72];
  __shared__ float bias_s[516];
  __shared__ int lag_s[2048];

  int blk = blockIdx.x;
  blk = (blk & 7) * 64 + (blk >> 3);  // bijective XCD swizzle (512 % 8 == 0)
  int qt = blk & 15;
  int h = (blk >> 4) & 15;
  int b = blk >> 8;
  int tid = threadIdx.x;
  int w = tid >> 6, l = tid & 63, g = l >> 4, c = l & 15;

  for (int i = tid; i < 513; i += 256) bias_s[i] = lag_bias[h * 513 + i] * 1.44269504f;
  for (int i = tid; i < 2048; i += 256) lag_s[i] = lag[i];

  int q0 = qt * 128 + w * 32;
  const bf16* qbase = qkv + (size_t)(b * 2048 + q0) * 3072 + h * 64;
  bf16x8 qf[2][2];
#pragma unroll
  for (int m = 0; m < 2; ++m)
#pragma unroll
    for (int kh = 0; kh < 2; ++kh)
      qf[m][kh] = *(const bf16x8*)(qbase + (size_t)(m * 16 + c) * 3072 + kh * 32 + g * 8);

  // fragment-read column offsets (XOR-swizzled LDS layout)
  int swz = (c & 7) << 3;
  int off0 = (g * 8) ^ swz;
  int off1 = off0 ^ 32;

  // staging: thread covers 16B; wave w owns rows w*16..w*16+15 (two 8-row chunks)
  int r0 = w * 16 + (l >> 3);
  int colE = ((l & 7) ^ (l >> 3)) << 3;  // inverse-swizzled global column
  const bf16* kbase = qkv + (size_t)(b * 2048) * 3072 + 1024 + h * 64;
  const bf16* vbase = vt + (size_t)(b * 16 + h) * 64 * 2048;
  const bf16* kg0 = kbase + (size_t)r0 * 3072 + colE;
  const bf16* kg1 = kbase + (size_t)(r0 + 8) * 3072 + colE;
  const bf16* vg0 = vbase + (size_t)r0 * 2048 + colE;
  const bf16* vg1 = vbase + (size_t)(r0 + 8) * 2048 + colE;

#define STAGE(KD, VD)                    \
  do {                                   \
    gload16(kg0, KD + w * 1024);         \
    gload16(kg1, KD + w * 1024 + 512);   \
    gload16(vg0, VD + w * 1024);         \
    gload16(vg1, VD + w * 1024 + 512);   \
    kg0 += 64 * 3072; kg1 += 64 * 3072;  \
    vg0 += 64; vg1 += 64;                \
  } while (0)

  // prologue: stage tile 0 into buffer 0; barrier drains vmcnt + bias/lag writes
  STAGE(Ks0, Vs0);
  __syncthreads();

  int lagq[2][4];
#pragma unroll
  for (int m = 0; m < 2; ++m)
#pragma unroll
    for (int j = 0; j < 4; ++j) lagq[m][j] = lag_s[q0 + m * 16 + g * 4 + j];

  f32x4 oacc[2][4] = {};
  float psum[2][4] = {};

#define TILE(KB, VB, KT)                                                          \
  do {                                                                            \
    f32x4 sf[2][4] = {};                                                          \
    int lagk[4];                                                                  \
    __builtin_amdgcn_s_setprio(1);                                                \
    _Pragma("unroll") for (int kb = 0; kb < 4; ++kb) {                            \
      int row = kb * 16 + c;                                                      \
      bf16x8 k0 = *(const bf16x8*)&KB[row * 64 + off0];                           \
      bf16x8 k1 = *(const bf16x8*)&KB[row * 64 + off1];                           \
      sf[0][kb] = mfma16(qf[0][0], k0, sf[0][kb]);                                \
      sf[0][kb] = mfma16(qf[0][1], k1, sf[0][kb]);                                \
      sf[1][kb] = mfma16(qf[1][0], k0, sf[1][kb]);                                \
      sf[1][kb] = mfma16(qf[1][1], k1, sf[1][kb]);                                \
      lagk[kb] = lag_s[(KT) + kb * 16 + c];                                       \
    }                                                                             \
    __builtin_amdgcn_s_setprio(0);                                                \
    _Pragma("unroll") for (int m = 0; m < 2; ++m)                                 \
    _Pragma("unroll") for (int kb = 0; kb < 4; ++kb)                              \
    _Pragma("unroll") for (int j = 0; j < 4; ++j) {                               \
      int ld = lagq[m][j] - lagk[kb];                                             \
      ld = ld < 0 ? -ld : ld;                                                     \
      float p = __builtin_amdgcn_exp2f(sf[m][kb][j] + bias_s[ld]);                \
      psum[m][j] += p;                                                            \
      Ps[w][m * 16 + g * 4 + j][kb * 16 + c] = (bf16)p;                           \
    }                                                                             \
    asm volatile("s_waitcnt lgkmcnt(0)" ::: "memory");                            \
    __builtin_amdgcn_s_setprio(1);                                                \
    _Pragma("unroll") for (int ph = 0; ph < 2; ++ph) {                            \
      bf16x8 pa0 = *(const bf16x8*)&Ps[w][c][ph * 32 + g * 8];                    \
      bf16x8 pa1 = *(const bf16x8*)&Ps[w][16 + c][ph * 32 + g * 8];               \
      int voff = ph ? off1 : off0;                                                \
      _Pragma("unroll") for (int n = 0; n < 4; ++n) {                             \
        bf16x8 vf = *(const bf16x8*)&VB[(n * 16 + c) * 64 + voff];                \
        oacc[0][n] = mfma16(pa0, vf, oacc[0][n]);                                 \
        oacc[1][n] = mfma16(pa1, vf, oacc[1][n]);                                 \
      }                                                                           \
    }                                                                             \
    __builtin_amdgcn_s_setprio(0);                                                \
  } while (0)

  for (int kt = 0; kt < 2048; kt += 128) {
    if (kt + 64 < 2048) STAGE(Ks1, Vs1);
    TILE(Ks0, Vs0, kt);
    __syncthreads();  // drains vmcnt: Ks1/Vs1 ready; closes Ks0/Vs0 reads
    if (kt + 128 < 2048) STAGE(Ks0, Vs0);
    TILE(Ks1, Vs1, kt + 64);
    __syncthreads();
  }

  // one-time row-sum reduction across the 16 c-lanes, then normalize+store
#pragma unroll
  for (int m = 0; m < 2; ++m) {
#pragma unroll
    for (int j = 0; j < 4; ++j) {
      float s = psum[m][j];
      s += __shfl_xor(s, 1);
      s += __shfl_xor(s, 2);
      s += __shfl_xor(s, 4);
      s += __shfl_xor(s, 8);
      float inv = 1.f / s;
      bf16* ob = out + (size_t)(b * 2048 + q0 + m * 16 + g * 4 + j) * 1024 + h * 64;
#pragma unroll
      for (int n = 0; n < 4; ++n)
        ob[n * 16 + c] = (bf16)(oacc[m][n][j] * inv);
    }
  }
#undef STAGE
#undef TILE
}

extern "C" void kernel_launch(void* const* d_in, const int* in_sizes, int n_in,
                              void* d_out, int out_size, void* d_ws, size_t ws_size,
                              hipStream_t stream) {
  const float* x        = (const float*)d_in[0];
  const int*   lag      = (const int*)d_in[1];
  const float* wq       = (const float*)d_in[2];
  const float* bq       = (const float*)d_in[3];
  const float* wk       = (const float*)d_in[4];
  const float* bk       = (const float*)d_in[5];
  const float* wv       = (const float*)d_in[6];
  const float* bv       = (const float*)d_in[7];
  const float* wo       = (const float*)d_in[8];
  const float* bo       = (const float*)d_in[9];
  const float* lag_bias = (const float*)d_in[10];

  char* ws = (char*)d_ws;
  bf16*  xb    = (bf16*)ws;                        // 8 MB
  bf16*  wqkvt = (bf16*)(ws + (8u  << 20));        // 6 MB
  bf16*  wot   = (bf16*)(ws + (14u << 20));        // 2 MB
  float* bqkv  = (float*)(ws + (16u << 20));       // 12 KB
  bf16*  qkv   = (bf16*)(ws + (17u << 20));        // 24 MB
  bf16*  vtb   = (bf16*)(ws + (41u << 20));        // 8 MB
  bf16*  aout  = (bf16*)(ws + (49u << 20));        // 8 MB

  cvt_x_kernel<<<2048, 256, 0, stream>>>(x, xb, 524288);
  cvt_wt_kernel<<<256, 256, 0, stream>>>(wq, wqkvt);
  cvt_wt_kernel<<<256, 256, 0, stream>>>(wk, wqkvt + (1u << 20));
  cvt_wt_kernel<<<256, 256, 0, stream>>>(wv, wqkvt + (2u << 20));
  cvt_wt_kernel<<<256, 256, 0, stream>>>(wo, wot);
  cvt_bias_kernel<<<12, 256, 0, stream>>>(bq, bk, bv, bqkv);
  gemm_bt_kernel<1><<<dim3(24, 32), 256, 0, stream>>>(
      xb, wqkvt, bqkv, qkv, 4096, 3072, 1024, 1024, 0.125f * 1.44269504f);
  transpose_v_kernel<<<1024, 256, 0, stream>>>(qkv, vtb);
  attn_kernel<<<512, 256, 0, stream>>>(qkv, vtb, lag, lag_bias, aout);
  gemm_bt_kernel<0><<<dim3(8, 32), 256, 0, stream>>>(
      aout, wot, bo, (float*)d_out, 4096, 1024, 1024, 0, 1.0f);
}